// Round 4
// baseline (243.534 us; speedup 1.0000x reference)
//
#include <hip/hip_runtime.h>
#include <climits>
#include <cmath>

// DetectPeaks: xcorr [16,1,256,8192] f32 -> (neighbor_score, topk_scores, topk_index), each [rows,3]
// rows = 4096, W = 8192.
// Round-8 structure: TWO-PASS, zero block coupling. Rounds 0-3 pinned data consumption at
// ~1.3 TB/s across occupancy 35-70%, LDS vs register staging, and schedule pinning; the one
// untouched structural element was the block phase-coupling (syncthreads + cross-wave merge +
// 1-of-256-lane serial epilogue, 16 sequential blocks/CU). This round removes it entirely:
//   pass 1: 16384 independent WAVES, one 2048-elem chunk each; wave-internal shuffle merge;
//           lane 0 writes a 32 B top-3 partial to d_ws (512 KB). No barriers, no LDS.
//   pass 2: 4096 threads, one row each: merge 4 partials, gather neighbor scores, write out.
// Decisive experiment: pass-1 at copy-bench-like BW => block coupling was the stall;
// pass-1 still ~1.3 TB/s => kernel structure exonerated (environment/HBM-path limit).

#define PW    8192
#define PNLAG (PW / 2)
#define BLOCK 256
#define NW    4                 // waves per block (pass 1)
#define J     8                 // float4 quads per lane: chunk = J*64*4 = 2048 elems
#define CHUNK 2048
#define CPR   4                 // chunks per row

__device__ __forceinline__ bool better(float av, int ai, float bv, int bi) {
  return (av > bv) || ((av == bv) && (ai < bi));   // lax.top_k: ties -> lower index
}

__device__ __forceinline__ void insert3_full(float v, int i,
                                             float &v0, int &i0,
                                             float &v1, int &i1,
                                             float &v2, int &i2) {
  if (better(v, i, v2, i2)) {
    if (better(v, i, v1, i1)) {
      if (better(v, i, v0, i0)) {
        v2 = v1; i2 = i1; v1 = v0; i1 = i0; v0 = v; i0 = i;
      } else {
        v2 = v1; i2 = i1; v1 = v; i1 = i;
      }
    } else {
      v2 = v; i2 = i;
    }
  }
}

// Exact float ties between distinct lags have ~0 probability; strict > suffices.
// Candidates arrive in ascending-index order per lane => incumbent-wins keeps lower index.
__device__ __forceinline__ void insert3_fast(float c, int ci,
                                             float &v0, int &i0,
                                             float &v1, int &i1,
                                             float &v2, int &i2) {
  const bool b2 = c > v2;
  const bool b1 = c > v1;
  const bool b0 = c > v0;
  v2 = b1 ? v1 : (b2 ? c : v2);  i2 = b1 ? i1 : (b2 ? ci : i2);
  v1 = b0 ? v0 : (b1 ? c : v1);  i1 = b0 ? i0 : (b1 ? ci : i1);
  v0 = b0 ? c  : v0;             i0 = b0 ? ci : i0;
}

__global__ __launch_bounds__(BLOCK, 4)
void peaks_pass1(const float* __restrict__ x, float* __restrict__ ws) {
  const int t     = threadIdx.x;
  const int lane  = t & 63;
  const int wave  = t >> 6;
  const int chunk = blockIdx.x * NW + wave;     // 0..16383, fully independent per wave
  const int row   = chunk >> 2;
  const int c     = chunk & 3;
  const float* __restrict__ xr = x + (size_t)row * PW;
  const int base  = c * CHUNK;

  // chunk-edge halos (row edges pad -inf per torch max_pool2d); wave-uniform loads
  const float edgeL = (base > 0)          ? xr[base - 1]     : -INFINITY;
  const float edgeR = (base + CHUNK < PW) ? xr[base + CHUNK] : -INFINITY;

  float4 q[J];
#pragma unroll
  for (int j = 0; j < J; ++j)
    q[j] = *(const float4*)(xr + base + (j * 64 + lane) * 4);

  float v0 = -INFINITY, v1 = -INFINITY, v2 = -INFINITY;
  int   i0 = INT_MAX,   i1 = INT_MAX,   i2 = INT_MAX;

#pragma unroll
  for (int j = 0; j < J; ++j) {
    const float4 v = q[j];

    // left halo = element p-1; right halo = element p+4
    float left = __shfl_up(v.w, 1);
    const float lf = (j == 0) ? edgeL : __shfl(q[j - 1].w, 63);
    if (lane == 0) left = lf;
    float right = __shfl_down(v.x, 1);
    const float rf = (j == J - 1) ? edgeR : __shfl(q[j + 1].x, 0);
    if (lane == 63) right = rf;

    const int p = base + (j * 64 + lane) * 4;   // first element index of this quad (in-row)

    // sliding 3-max over the 4 positions
    const float p01 = fmaxf(v.x, v.y);
    const float p12 = fmaxf(v.y, v.z);
    const float p23 = fmaxf(v.z, v.w);
    const float m0 = fmaxf(left, p01);
    const float m1 = fmaxf(p01, v.z);
    const float m2 = fmaxf(p12, v.w);
    const float m3 = fmaxf(p23, right);

    // NMS score: x where local max else 0
    const float s0 = (v.x == m0) ? v.x : 0.0f;
    const float s1 = (v.y == m1) ? v.y : 0.0f;
    const float s2 = (v.z == m2) ? v.z : 0.0f;
    const float s3 = (v.w == m3) ? v.w : 0.0f;

    // quad top-2 (>= keeps lower index on ties); a 4-window holds <=2 local maxima
    const bool  a01 = s0 >= s1;
    const float hiA = a01 ? s0 : s1;   const int hiAi = a01 ? p     : p + 1;
    const float loA = a01 ? s1 : s0;   const int loAi = a01 ? p + 1 : p;
    const bool  a23 = s2 >= s3;
    const float hiB = a23 ? s2 : s3;   const int hiBi = a23 ? p + 2 : p + 3;
    const float loB = a23 ? s3 : s2;   const int loBi = a23 ? p + 3 : p + 2;

    const bool  ab  = hiA >= hiB;
    const float c1  = ab ? hiA : hiB;  const int c1i = ab ? hiAi : hiBi;
    const bool  sb  = ab ? (loA >= hiB) : (hiA >= loB);
    const float c2  = ab ? (sb ? loA : hiB) : (sb ? hiA : loB);
    const int   c2i = ab ? (sb ? loAi : hiBi) : (sb ? hiAi : loBi);

    insert3_fast(c1, c1i, v0, i0, v1, i1, v2, i2);
    insert3_fast(c2, c2i, v0, i0, v1, i1, v2, i2);
  }

  // wave-level tree merge (64 lanes) — no LDS, no barrier
#pragma unroll
  for (int off = 32; off > 0; off >>= 1) {
    float ov0 = __shfl_down(v0, off);
    int   oi0 = __shfl_down(i0, off);
    float ov1 = __shfl_down(v1, off);
    int   oi1 = __shfl_down(i1, off);
    float ov2 = __shfl_down(v2, off);
    int   oi2 = __shfl_down(i2, off);
    if (lane + off < 64) {
      insert3_full(ov0, oi0, v0, i0, v1, i1, v2, i2);
      insert3_full(ov1, oi1, v0, i0, v1, i1, v2, i2);
      insert3_full(ov2, oi2, v0, i0, v1, i1, v2, i2);
    }
  }

  if (lane == 0) {
    float* o = ws + (size_t)chunk * 8;          // 32 B per chunk partial
    float4 vv; vv.x = v0; vv.y = v1; vv.z = v2; vv.w = 0.0f;
    *(float4*)o = vv;
    int4 ii; ii.x = i0; ii.y = i1; ii.z = i2; ii.w = 0;
    *(int4*)(o + 4) = ii;
  }
}

__global__ __launch_bounds__(BLOCK)
void peaks_pass2(const float* __restrict__ x, const float* __restrict__ ws,
                 float* __restrict__ out, int rows) {
  const int row = blockIdx.x * BLOCK + threadIdx.x;
  if (row >= rows) return;

  float v0 = -INFINITY, v1 = -INFINITY, v2 = -INFINITY;
  int   i0 = INT_MAX,   i1 = INT_MAX,   i2 = INT_MAX;

#pragma unroll
  for (int c = 0; c < CPR; ++c) {               // ascending chunk order: ties -> lower index
    const float* o = ws + ((size_t)row * CPR + c) * 8;
    const float4 vv = *(const float4*)o;
    const int4   ii = *(const int4*)(o + 4);
    insert3_full(vv.x, ii.x, v0, i0, v1, i1, v2, i2);
    insert3_full(vv.y, ii.y, v0, i0, v1, i1, v2, i2);
    insert3_full(vv.z, ii.z, v0, i0, v1, i1, v2, i2);
  }

  const float* __restrict__ xr = x + (size_t)row * PW;
  float* __restrict__ nb = out;                      // neighbor_score
  float* __restrict__ ts = out + (size_t)rows * 3;   // topk_scores
  float* __restrict__ ti = out + (size_t)rows * 6;   // topk_index (as float)

  const int top = i0;
#pragma unroll
  for (int k = 0; k < 3; ++k) {
    int idx = top - 1 + k;
    idx = idx < 0 ? 0 : (idx > PW - 1 ? PW - 1 : idx);
    nb[row * 3 + k] = xr[idx];
  }
  ts[row * 3 + 0] = v0;
  ts[row * 3 + 1] = v1;
  ts[row * 3 + 2] = v2;
  ti[row * 3 + 0] = (float)(i0 - PNLAG);
  ti[row * 3 + 1] = (float)(i1 - PNLAG);
  ti[row * 3 + 2] = (float)(i2 - PNLAG);
}

extern "C" void kernel_launch(void* const* d_in, const int* in_sizes, int n_in,
                              void* d_out, int out_size, void* d_ws, size_t ws_size,
                              hipStream_t stream) {
  const float* x = (const float*)d_in[0];
  float* out = (float*)d_out;
  float* ws  = (float*)d_ws;                    // needs rows*CPR*32 B = 512 KB
  const int rows = in_sizes[0] / PW;            // 4096

  peaks_pass1<<<rows * CPR / NW, BLOCK, 0, stream>>>(x, ws);
  peaks_pass2<<<(rows + BLOCK - 1) / BLOCK, BLOCK, 0, stream>>>(x, ws, out, rows);
}